// Round 3
// baseline (842.630 us; speedup 1.0000x reference)
//
#include <hip/hip_runtime.h>
#include <hip/hip_bf16.h>

#define NN 10000
#define NE 320000
#define SIG 0.3f
#define NDp ((size_t)1280000)          // NN*128
#define OUT_H ((size_t)0)
#define OUT_E ((size_t)1280000)
#define OUT_P ((size_t)42240000)
#define OUT_D ((size_t)43520000)

// ws layout (float index): 8 node-linear outputs, fab, cnt, flags, staged bf16
#define F_V1H (0 * NDp)
#define F_V2H (1 * NDp)
#define F_P1H (2 * NDp)
#define F_P2H (3 * NDp)
#define F_P3H (4 * NDp)
#define F_D1H (5 * NDp)
#define F_D2H (6 * NDp)
#define F_G   (7 * NDp)
#define F_FAB (8 * NDp)
#define F_CNT (9 * NDp)
#define F_FLAGS (9 * NDp + 10240)       // 16 ints
#define F_STAGED (9 * NDp + 10240 + 16) // staged ushort region starts here
// staged (ushort index within staged region)
#define S_H  ((size_t)0)
#define S_P  ((size_t)1280000)
#define S_D  ((size_t)2560000)
#define S_W  ((size_t)3840000)          // 9 x 16384 (V1,V2,E1,P1,P2,P3,D1,D2,V)
#define S_WT (S_W + 9 * 16384)          // 32768
// staged region = S_WT + 32768 = 4020224 ushorts = 2010112 floats
// XCD-private fab copies (8 x NDp floats), used only if workspace is big enough
#define F_FABX8 (F_STAGED + (size_t)2010112)

typedef __attribute__((ext_vector_type(8))) short s8v;
typedef __attribute__((ext_vector_type(4))) float f4v;

__device__ __forceinline__ float b2f(unsigned short s) {
  return __uint_as_float(((unsigned int)s) << 16);
}
__device__ __forceinline__ short f2b(float f) {
  __hip_bfloat16 b = __float2bfloat16(f);
  return *reinterpret_cast<short*>(&b);
}
__device__ __forceinline__ float lrelu(float x) { return x >= 0.f ? x : 0.01f * x; }
__device__ __forceinline__ float loadf(const void* p, size_t i, bool f32) {
  return f32 ? ((const float*)p)[i] : b2f(((const unsigned short*)p)[i]);
}
// paired load (i even): float2 or packed 2xbf16
__device__ __forceinline__ float2 loadf2(const void* p, size_t i, bool f32) {
  if (f32) return *reinterpret_cast<const float2*>((const float*)p + i);
  unsigned int w = *((const unsigned int*)p + (i >> 1));
  return make_float2(b2f((unsigned short)(w & 0xFFFF)), b2f((unsigned short)(w >> 16)));
}
// paired store (i even): float2 or packed 2xbf16
__device__ __forceinline__ void storef2(void* p, size_t i, float x, float y, bool f32) {
  if (f32) {
    *reinterpret_cast<float2*>((float*)p + i) = make_float2(x, y);
  } else {
    unsigned int v = ((unsigned int)(unsigned short)f2b(y) << 16) |
                     (unsigned int)(unsigned short)f2b(x);
    *((unsigned int*)p + (i >> 1)) = v;
  }
}
// vectorized f32->bf16x8 (16B-aligned src)
__device__ __forceinline__ s8v cvt8(const float* fp) {
  f4v a = *reinterpret_cast<const f4v*>(fp);
  f4v b = *reinterpret_cast<const f4v*>(fp + 4);
  s8v r;
#pragma unroll
  for (int j = 0; j < 4; j++) { r[j] = f2b(a[j]); r[4 + j] = f2b(b[j]); }
  return r;
}

// ---------------- zero fab copies/cnt/flags ----------------
__global__ __launch_bounds__(256) void zero_kernel(float* ws, float* fabBase, int fabFloats) {
  int i = blockIdx.x * 256 + threadIdx.x;  // grid = fabFloats/256 exactly
  fabBase[i] = 0.f;
  if (i < NN) ws[F_CNT + i] = 0.f;
  if (i < 16) ((int*)(ws + F_FLAGS))[i] = 0;
}

// ---------------- dtype detection: bf16-NaN bit patterns <=> buffer is f32 ----------------
struct DetTask { const unsigned short* s; int n; int flag; };
struct DetArgs { DetTask t[6]; int* flags; };
__global__ __launch_bounds__(256) void detect_kernel(DetArgs a) {
  DetTask t = a.t[blockIdx.y];
  int hit = 0;
  for (int i = blockIdx.x * 256 + threadIdx.x; i < t.n; i += gridDim.x * 256) {
    if ((unsigned short)(t.s[i] & 0x7FFF) > (unsigned short)0x7F80) hit = 1;
  }
  if (hit) atomicOr(&a.flags[t.flag], 1);
}

// ---------------- stage tensors as canonical bf16 ----------------
struct ConvTask { const void* src; unsigned short* dst; int n; int flag; };
struct ConvArgs { ConvTask t[13]; const int* flags; };
__global__ __launch_bounds__(256) void convert_kernel(ConvArgs a) {
  ConvTask t = a.t[blockIdx.y];
  bool f32 = a.flags[t.flag] != 0;
  for (int i = blockIdx.x * 256 + threadIdx.x; i < t.n; i += gridDim.x * 256) {
    t.dst[i] = f32 ? (unsigned short)f2b(((const float*)t.src)[i])
                   : ((const unsigned short*)t.src)[i];
  }
}

// ---------------- count non-spatial in-edges per dst ----------------
__global__ __launch_bounds__(256) void cnt_kernel(const int* __restrict__ spatial,
                                                  const int* __restrict__ dst,
                                                  float* __restrict__ cnt) {
  int e = blockIdx.x * 256 + threadIdx.x;
  if (e < NE && spatial[e] != 1) atomicAdd(&cnt[dst[e]], 1.0f);
}

// ---------------- fused node linears (V1,V2,P1,P2,P3,D1,D2,T) ----------------
struct NodeArgs {
  const unsigned short* x[3];  // staged h, p, d
  const unsigned short* W[8];  // staged weights (bf16)
  const void* b[8];            // raw biases (adaptive)
  float* out[8];
  const int* flags;
};

__global__ __launch_bounds__(256) void node_gemm_kernel(NodeArgs a) {
  const int o = blockIdx.y;
  const int wave = threadIdx.x >> 6, lane = threadIdx.x & 63;
  const int l16 = lane & 15, quad = lane >> 4;
  const int m0 = blockIdx.x * 64 + wave * 16;
  if (m0 >= NN) return;
  const bool wf32 = a.flags[5] != 0;
  int arow = m0 + l16;
  if (arow >= NN) arow = NN - 1;
  const unsigned short* Wp = a.W[o];
  f4v acc[8] = {};
  if (o < 7) {
    const unsigned short* X0 = (o < 2) ? a.x[0] : (o < 5 ? a.x[1] : a.x[2]);
    const unsigned short* xrow = X0 + (size_t)arow * 128;
#pragma unroll
    for (int kk = 0; kk < 128; kk += 32) {
      int k8 = kk + quad * 8;
      s8v av = *(const s8v*)(xrow + k8);
#pragma unroll
      for (int nt = 0; nt < 8; nt++) {
        s8v bv = *(const s8v*)(Wp + (size_t)(nt * 16 + l16) * 128 + k8);
        acc[nt] = __builtin_amdgcn_mfma_f32_16x16x32_bf16(av, bv, acc[nt], 0, 0, 0);
      }
    }
  } else {  // W_T: K=256, input = [h | d]
#pragma unroll
    for (int kk = 0; kk < 256; kk += 32) {
      int k8 = kk + quad * 8;
      const unsigned short* ap = (k8 < 128) ? (a.x[0] + (size_t)arow * 128 + k8)
                                            : (a.x[2] + (size_t)arow * 128 + (k8 - 128));
      s8v av = *(const s8v*)ap;
#pragma unroll
      for (int nt = 0; nt < 8; nt++) {
        s8v bv = *(const s8v*)(Wp + (size_t)(nt * 16 + l16) * 256 + k8);
        acc[nt] = __builtin_amdgcn_mfma_f32_16x16x32_bf16(av, bv, acc[nt], 0, 0, 0);
      }
    }
  }
  float* outp = a.out[o];
#pragma unroll
  for (int nt = 0; nt < 8; nt++) {
    int col = nt * 16 + l16;
    float bvv = loadf(a.b[o], col, wf32);
#pragma unroll
    for (int r = 0; r < 4; r++) {
      int row = m0 + quad * 4 + r;
      if (row < NN) {
        float v = acc[nt][r] + bvv;
        if (o == 7) v = fmaxf(v, 0.f);
        outp[(size_t)row * 128 + col] = v;
      }
    }
  }
}

// ---------------- fused edge kernel ----------------
// Per wave: 16 edges (sequential). Phase A: Vj GEMM -> sv (LDS). Phase B: E1
// GEMM -> E1 (bf16) into per-wave LDS. Epilogue: row loop, wave-uniform
// indices, 2 cols/lane, coalesced float2 gathers; e re-read is same-XCD
// L2-hot (streamed by this wave in Phase B). fab atomics go to an
// XCD-private copy (blockIdx&7 ~ XCD under round-robin dispatch) so the
// RMW lines stay in one XCD's L2 instead of ping-ponging via HBM.
#define LSTRIDE 136  // 128 + 8 pad (ushorts)
__global__ __launch_bounds__(256) void edge_kernel(
    const void* __restrict__ e, const unsigned short* __restrict__ sh,
    const int* __restrict__ spatial, const int* __restrict__ src, const int* __restrict__ dst,
    const unsigned short* __restrict__ WE1, const unsigned short* __restrict__ WV,
    const void* __restrict__ bE1, const void* __restrict__ bV,
    const float* __restrict__ P1h, const float* __restrict__ P2h,
    float* __restrict__ fab, int fabMask,
    void* __restrict__ out, const int* __restrict__ flags) {
  __shared__ __align__(16) unsigned short lds_E1[4][16 * LSTRIDE];
  __shared__ float lds_sv[4][16];
  const int wave = threadIdx.x >> 6, lane = threadIdx.x & 63;
  const int l16 = lane & 15, quad = lane >> 4;
  const int m0 = blockIdx.x * 64 + wave * 16;  // NE % 64 == 0
  const bool ef32 = flags[1] != 0;
  const bool wf32 = flags[5] != 0;
  const bool of32 = (flags[0] | flags[1] | flags[2] | flags[3] | flags[4] | flags[5]) != 0;
  const int arow = m0 + l16;
  float* __restrict__ fabW = fab + (size_t)(blockIdx.x & fabMask) * NDp;

  // ---- Phase A: Vj GEMM, reduced immediately to sv, parked in LDS ----
  {
    f4v acc2[8] = {};
    const int asrc = src[arow], adst = dst[arow];
    const unsigned short* hs_row = sh + (size_t)asrc * 128;
    const unsigned short* hd_row = sh + (size_t)adst * 128;
#pragma unroll
    for (int kk = 0; kk < 128; kk += 32) {
      int k8 = kk + quad * 8;
      s8v hs = *(const s8v*)(hs_row + k8);
      s8v hd = *(const s8v*)(hd_row + k8);
      s8v ap;
#pragma unroll
      for (int j = 0; j < 8; j++)
        ap[j] = f2b(b2f((unsigned short)hs[j]) * b2f((unsigned short)hd[j]));
#pragma unroll
      for (int nt = 0; nt < 8; nt++) {
        s8v bv = *(const s8v*)(WV + (size_t)(nt * 16 + l16) * 128 + k8);
        acc2[nt] = __builtin_amdgcn_mfma_f32_16x16x32_bf16(ap, bv, acc2[nt], 0, 0, 0);
      }
    }
    float sv[4] = {0.f, 0.f, 0.f, 0.f};
#pragma unroll
    for (int nt = 0; nt < 8; nt++) {
      int col = nt * 16 + l16;
      float bvv = loadf(bV, col, wf32);
#pragma unroll
      for (int r = 0; r < 4; r++) sv[r] += fmaxf(acc2[nt][r] + bvv, 0.f);
    }
#pragma unroll
    for (int m = 1; m < 16; m <<= 1) {
#pragma unroll
      for (int r = 0; r < 4; r++) sv[r] += __shfl_xor(sv[r], m, 64);
    }
    if (l16 == 0) {
#pragma unroll
      for (int r = 0; r < 4; r++) lds_sv[wave][quad * 4 + r] = sv[r];
    }
  }

  // ---- Phase B: E1 GEMM; park E1 (bf16) in LDS ----
  {
    f4v acc1[8] = {};
    size_t ro = (size_t)arow * 128;
#pragma unroll
    for (int kk = 0; kk < 128; kk += 32) {
      int k8 = kk + quad * 8;
      s8v av;
      if (ef32) av = cvt8((const float*)e + ro + k8);
      else av = *(const s8v*)((const unsigned short*)e + ro + k8);
#pragma unroll
      for (int nt = 0; nt < 8; nt++) {
        s8v bv = *(const s8v*)(WE1 + (size_t)(nt * 16 + l16) * 128 + k8);
        acc1[nt] = __builtin_amdgcn_mfma_f32_16x16x32_bf16(av, bv, acc1[nt], 0, 0, 0);
      }
    }
#pragma unroll
    for (int nt = 0; nt < 8; nt++) {
      int col = nt * 16 + l16;
      float bvv = loadf(bE1, col, wf32);
#pragma unroll
      for (int r = 0; r < 4; r++) {
        int row = quad * 4 + r;
        lds_E1[wave][row * LSTRIDE + col] = (unsigned short)f2b(acc1[nt][r] + bvv);
      }
    }
  }
  // per-wave LDS only: same-wave write->read, compiler inserts lgkmcnt waits

  // ---- Epilogue: 16 rows, wave-uniform indices, 2 cols per lane ----
  const int c0 = lane * 2;
#pragma unroll 4
  for (int row = 0; row < 16; row++) {
    const int er = m0 + row;
    const int sr_ = src[er], dr_ = dst[er], sp_ = spatial[er];  // uniform
    float2 p1 = *(const float2*)(P1h + (size_t)dr_ * 128 + c0);
    float2 p2 = *(const float2*)(P2h + (size_t)sr_ * 128 + c0);
    unsigned int e1w = *(const unsigned int*)&lds_E1[wave][row * LSTRIDE + c0];
    float e1x = b2f((unsigned short)(e1w & 0xFFFF));
    float e1y = b2f((unsigned short)(e1w >> 16));
    float2 ee = loadf2(e, (size_t)er * 128 + c0, ef32);  // L2-hot re-read
    float vx = 0.5f * (p1.x - p2.x + e1x);
    float vy = 0.5f * (p1.y - p2.y + e1y);
    storef2(out, OUT_E + (size_t)er * 128 + c0, ee.x + lrelu(vx), ee.y + lrelu(vy), of32);
    float n2 = vx * vx + vy * vy;
#pragma unroll
    for (int m = 1; m < 64; m <<= 1) n2 += __shfl_xor(n2, m, 64);
    if (sp_ == 1) {
      float n = sqrtf(n2);
      if (n >= 1e-9f) {
        float svr = lds_sv[wave][row];
        float rr = 0.5f * sqrtf(n);
        float s = expf(-rr / SIG);
        float c = -svr * s * 0.25f / (SIG * n * sqrtf(n));
        atomicAdd(&fabW[(size_t)dr_ * 128 + c0], c * vx);
        atomicAdd(&fabW[(size_t)dr_ * 128 + c0 + 1], c * vy);
      }
    }
  }
}

// ---------------- node finalize ----------------
__global__ __launch_bounds__(256) void node_out_kernel(
    const unsigned short* __restrict__ sh, const unsigned short* __restrict__ sp,
    const unsigned short* __restrict__ sd, const void* __restrict__ dt,
    const float* __restrict__ V1h, const float* __restrict__ V2h, const float* __restrict__ P3h,
    const float* __restrict__ D1h, const float* __restrict__ D2h, const float* __restrict__ g,
    const float* __restrict__ fab, int ncopy, const float* __restrict__ cnt,
    void* __restrict__ out, const int* __restrict__ flags) {
  const int wave = threadIdx.x >> 6, lane = threadIdx.x & 63;
  const int node = blockIdx.x * 4 + wave;  // NN % 4 == 0
  const bool dtf32 = flags[4] != 0;
  const bool of32 = (flags[0] | flags[1] | flags[2] | flags[3] | flags[4] | flags[5]) != 0;
  const size_t i = (size_t)node * 128 + lane * 2;
  float cn = cnt[node];
  float2 v1 = *(const float2*)(V1h + i);
  float2 d1 = *(const float2*)(D1h + i);
  float2 gg = *(const float2*)(g + i);
  float2 fb = make_float2(0.f, 0.f);
  for (int k = 0; k < ncopy; k++) {
    float2 t = *(const float2*)(fab + (size_t)k * NDp + i);
    fb.x += t.x; fb.y += t.y;
  }
  float fx = (d1.x - v1.x) * (cn * gg.x) - fb.x;
  float fy = (d1.y - v1.y) * (cn * gg.y) - fb.y;
  float n2 = fx * fx + fy * fy;
#pragma unroll
  for (int m = 1; m < 64; m <<= 1) n2 += __shfl_xor(n2, m, 64);
  float nf = sqrtf(n2);
  float dtv = loadf(dt, node, dtf32);
  float2 v2 = *(const float2*)(V2h + i);
  float2 p3 = *(const float2*)(P3h + i);
  float2 d2 = *(const float2*)(D2h + i);
  float hx = v2.x + fx * dtv, hy = v2.y + fy * dtv;
  float px = p3.x + fx * dtv + 0.5f * fx * dtv * dtv;
  float py = p3.y + fy * dtv + 0.5f * fy * dtv * dtv;
  float invn = 1.f / (nf + 1e-9f);
  float dx = d2.x + fx * invn, dy = d2.y + fy * invn;
  storef2(out, OUT_H + i, b2f(sh[i]) + lrelu(hx), b2f(sh[i + 1]) + lrelu(hy), of32);
  storef2(out, OUT_P + i, b2f(sp[i]) + lrelu(px), b2f(sp[i + 1]) + lrelu(py), of32);
  storef2(out, OUT_D + i, b2f(sd[i]) + lrelu(dx), b2f(sd[i + 1]) + lrelu(dy), of32);
}

extern "C" void kernel_launch(void* const* d_in, const int* in_sizes, int n_in,
                              void* d_out, int out_size, void* d_ws, size_t ws_size,
                              hipStream_t stream) {
  const int* spatial = (const int*)d_in[5];
  const int* src = (const int*)d_in[6];
  const int* dst = (const int*)d_in[7];

  float* ws = (float*)d_ws;
  int* flags = (int*)(ws + F_FLAGS);
  unsigned short* stg = (unsigned short*)(ws + F_STAGED);

  // XCD-private fab copies if workspace allows (95.2 MB needed), else 1 copy
  const bool have8 = ws_size >= (size_t)(F_FABX8 + 8 * NDp) * 4;
  float* fabBase = ws + (have8 ? F_FABX8 : F_FAB);
  const int fabMask = have8 ? 7 : 0;
  const int ncopy = have8 ? 8 : 1;
  const int fabFloats = (int)(ncopy * NDp);

  zero_kernel<<<fabFloats / 256, 256, 0, stream>>>(ws, fabBase, fabFloats);

  DetArgs da;
  da.t[0] = { (const unsigned short*)d_in[0], 1280000, 0 };
  da.t[1] = { (const unsigned short*)d_in[1], 40960000, 1 };
  da.t[2] = { (const unsigned short*)d_in[2], 1280000, 2 };
  da.t[3] = { (const unsigned short*)d_in[3], 1280000, 3 };
  da.t[4] = { (const unsigned short*)d_in[4], 10000, 4 };
  da.t[5] = { (const unsigned short*)d_in[8], 16384, 5 };
  da.flags = flags;
  detect_kernel<<<dim3(1024, 6), 256, 0, stream>>>(da);

  ConvArgs ca;
  ca.t[0] = { d_in[0], stg + S_H, 1280000, 0 };
  ca.t[1] = { d_in[2], stg + S_P, 1280000, 2 };
  ca.t[2] = { d_in[3], stg + S_D, 1280000, 3 };
  for (int i = 0; i < 9; i++)
    ca.t[3 + i] = { d_in[8 + 2 * i], stg + S_W + (size_t)i * 16384, 16384, 5 };
  ca.t[12] = { d_in[26], stg + S_WT, 32768, 5 };
  ca.flags = flags;
  convert_kernel<<<dim3(640, 13), 256, 0, stream>>>(ca);

  cnt_kernel<<<NE / 256, 256, 0, stream>>>(spatial, dst, ws + F_CNT);

  NodeArgs na;
  na.x[0] = stg + S_H; na.x[1] = stg + S_P; na.x[2] = stg + S_D;
  na.W[0] = stg + S_W + 0 * 16384;  na.b[0] = d_in[9];   // V1
  na.W[1] = stg + S_W + 1 * 16384;  na.b[1] = d_in[11];  // V2
  na.W[2] = stg + S_W + 3 * 16384;  na.b[2] = d_in[15];  // P1
  na.W[3] = stg + S_W + 4 * 16384;  na.b[3] = d_in[17];  // P2
  na.W[4] = stg + S_W + 5 * 16384;  na.b[4] = d_in[19];  // P3
  na.W[5] = stg + S_W + 6 * 16384;  na.b[5] = d_in[21];  // D1
  na.W[6] = stg + S_W + 7 * 16384;  na.b[6] = d_in[23];  // D2
  na.W[7] = stg + S_WT;             na.b[7] = d_in[27];  // T
  na.out[0] = ws + F_V1H; na.out[1] = ws + F_V2H; na.out[2] = ws + F_P1H;
  na.out[3] = ws + F_P2H; na.out[4] = ws + F_P3H; na.out[5] = ws + F_D1H;
  na.out[6] = ws + F_D2H; na.out[7] = ws + F_G;
  na.flags = flags;
  node_gemm_kernel<<<dim3((NN + 63) / 64, 8), 256, 0, stream>>>(na);

  edge_kernel<<<NE / 64, 256, 0, stream>>>(
      d_in[1], stg + S_H, spatial, src, dst,
      stg + S_W + 2 * 16384, stg + S_W + 8 * 16384, d_in[13], d_in[25],
      ws + F_P1H, ws + F_P2H, fabBase, fabMask, d_out, flags);

  node_out_kernel<<<NN / 4, 256, 0, stream>>>(
      stg + S_H, stg + S_P, stg + S_D, d_in[4],
      ws + F_V1H, ws + F_V2H, ws + F_P3H, ws + F_D1H, ws + F_D2H, ws + F_G,
      fabBase, ncopy, ws + F_CNT, d_out, flags);
}

// Round 4
// 784.342 us; speedup vs baseline: 1.0743x; 1.0743x over previous
//
#include <hip/hip_runtime.h>
#include <hip/hip_bf16.h>

#define NN 10000
#define NE 320000
#define SIG 0.3f
#define NDp ((size_t)1280000)          // NN*128
#define OUT_H ((size_t)0)
#define OUT_E ((size_t)1280000)
#define OUT_P ((size_t)42240000)
#define OUT_D ((size_t)43520000)

// ws layout (float index)
#define F_V1H (0 * NDp)
#define F_V2H (1 * NDp)
#define F_P1H (2 * NDp)
#define F_P2H (3 * NDp)
#define F_P3H (4 * NDp)
#define F_D1H (5 * NDp)
#define F_D2H (6 * NDp)
#define F_G   (7 * NDp)
#define F_FAB (8 * NDp)
#define F_CNT (9 * NDp)
#define F_FLAGS (9 * NDp + 10240)       // 16 ints
#define F_STAGED (9 * NDp + 10240 + 16) // staged ushort region starts here
// staged (ushort index within staged region)
#define S_H  ((size_t)0)
#define S_P  ((size_t)1280000)
#define S_D  ((size_t)2560000)
#define S_W  ((size_t)3840000)          // 9 x 16384 (V1,V2,E1,P1,P2,P3,D1,D2,V)
#define S_WT (S_W + 9 * 16384)          // 32768
// staged region = S_WT + 32768 = 4020224 ushorts = 2010112 floats
#define F_SV (F_STAGED + (size_t)2010112)  // NE floats (sum of relu(Vj) per edge)

typedef __attribute__((ext_vector_type(8))) short s8v;
typedef __attribute__((ext_vector_type(4))) float f4v;

__device__ __forceinline__ float b2f(unsigned short s) {
  return __uint_as_float(((unsigned int)s) << 16);
}
__device__ __forceinline__ short f2b(float f) {
  __hip_bfloat16 b = __float2bfloat16(f);
  return *reinterpret_cast<short*>(&b);
}
__device__ __forceinline__ float lrelu(float x) { return x >= 0.f ? x : 0.01f * x; }
__device__ __forceinline__ float loadf(const void* p, size_t i, bool f32) {
  return f32 ? ((const float*)p)[i] : b2f(((const unsigned short*)p)[i]);
}
// paired load (i even): float2 or packed 2xbf16
__device__ __forceinline__ float2 loadf2(const void* p, size_t i, bool f32) {
  if (f32) return *reinterpret_cast<const float2*>((const float*)p + i);
  unsigned int w = *((const unsigned int*)p + (i >> 1));
  return make_float2(b2f((unsigned short)(w & 0xFFFF)), b2f((unsigned short)(w >> 16)));
}
// paired store (i even): float2 or packed 2xbf16
__device__ __forceinline__ void storef2(void* p, size_t i, float x, float y, bool f32) {
  if (f32) {
    *reinterpret_cast<float2*>((float*)p + i) = make_float2(x, y);
  } else {
    unsigned int v = ((unsigned int)(unsigned short)f2b(y) << 16) |
                     (unsigned int)(unsigned short)f2b(x);
    *((unsigned int*)p + (i >> 1)) = v;
  }
}
// vectorized f32->bf16x8 (16B-aligned src)
__device__ __forceinline__ s8v cvt8(const float* fp) {
  f4v a = *reinterpret_cast<const f4v*>(fp);
  f4v b = *reinterpret_cast<const f4v*>(fp + 4);
  s8v r;
#pragma unroll
  for (int j = 0; j < 4; j++) { r[j] = f2b(a[j]); r[4 + j] = f2b(b[j]); }
  return r;
}

// ---------------- zero fab/cnt/flags ----------------
__global__ __launch_bounds__(256) void zero_kernel(float* ws) {
  int i = blockIdx.x * 256 + threadIdx.x;  // grid = NDp/256 exactly
  ws[F_FAB + i] = 0.f;
  if (i < NN) ws[F_CNT + i] = 0.f;
  if (i < 16) ((int*)(ws + F_FLAGS))[i] = 0;
}

// ---------------- dtype detection (vectorized uint4 = 8 halves/iter) ----------------
struct DetTask { const unsigned short* s; int n; int flag; };
struct DetArgs { DetTask t[6]; int* flags; };
__global__ __launch_bounds__(256) void detect_kernel(DetArgs a) {
  DetTask t = a.t[blockIdx.y];
  int hit = 0;
  const uint4* s4 = (const uint4*)t.s;
  const int n8 = t.n >> 3;  // all n divisible by 8
  for (int i = blockIdx.x * 256 + threadIdx.x; i < n8; i += gridDim.x * 256) {
    uint4 v = s4[i];
    unsigned int ww[4] = {v.x, v.y, v.z, v.w};
#pragma unroll
    for (int j = 0; j < 4; j++) {
      if ((unsigned short)(ww[j] & 0x7FFF) > (unsigned short)0x7F80) hit = 1;
      if ((unsigned short)((ww[j] >> 16) & 0x7FFF) > (unsigned short)0x7F80) hit = 1;
    }
  }
  if (hit) atomicOr(&a.flags[t.flag], 1);
}

// ---------------- stage tensors as canonical bf16 (vectorized 8/iter) ----------------
struct ConvTask { const void* src; unsigned short* dst; int n; int flag; };
struct ConvArgs { ConvTask t[13]; const int* flags; };
__global__ __launch_bounds__(256) void convert_kernel(ConvArgs a) {
  ConvTask t = a.t[blockIdx.y];
  bool f32 = a.flags[t.flag] != 0;
  const int n8 = t.n >> 3;  // all n divisible by 8
  for (int i = blockIdx.x * 256 + threadIdx.x; i < n8; i += gridDim.x * 256) {
    if (f32) ((s8v*)t.dst)[i] = cvt8((const float*)t.src + (size_t)i * 8);
    else ((uint4*)t.dst)[i] = ((const uint4*)t.src)[i];
  }
}

// ---------------- count non-spatial in-edges per dst ----------------
__global__ __launch_bounds__(256) void cnt_kernel(const int* __restrict__ spatial,
                                                  const int* __restrict__ dst,
                                                  float* __restrict__ cnt) {
  int e = blockIdx.x * 256 + threadIdx.x;
  if (e < NE && spatial[e] != 1) atomicAdd(&cnt[dst[e]], 1.0f);
}

// ---------------- fused node linears (V1,V2,P1,P2,P3,D1,D2,T) ----------------
struct NodeArgs {
  const unsigned short* x[3];  // staged h, p, d
  const unsigned short* W[8];  // staged weights (bf16)
  const void* b[8];            // raw biases (adaptive)
  float* out[8];
  const int* flags;
};

__global__ __launch_bounds__(256) void node_gemm_kernel(NodeArgs a) {
  const int o = blockIdx.y;
  const int wave = threadIdx.x >> 6, lane = threadIdx.x & 63;
  const int l16 = lane & 15, quad = lane >> 4;
  const int m0 = blockIdx.x * 64 + wave * 16;
  if (m0 >= NN) return;
  const bool wf32 = a.flags[5] != 0;
  int arow = m0 + l16;
  if (arow >= NN) arow = NN - 1;
  const unsigned short* Wp = a.W[o];
  f4v acc[8] = {};
  if (o < 7) {
    const unsigned short* X0 = (o < 2) ? a.x[0] : (o < 5 ? a.x[1] : a.x[2]);
    const unsigned short* xrow = X0 + (size_t)arow * 128;
#pragma unroll
    for (int kk = 0; kk < 128; kk += 32) {
      int k8 = kk + quad * 8;
      s8v av = *(const s8v*)(xrow + k8);
#pragma unroll
      for (int nt = 0; nt < 8; nt++) {
        s8v bv = *(const s8v*)(Wp + (size_t)(nt * 16 + l16) * 128 + k8);
        acc[nt] = __builtin_amdgcn_mfma_f32_16x16x32_bf16(av, bv, acc[nt], 0, 0, 0);
      }
    }
  } else {  // W_T: K=256, input = [h | d]
#pragma unroll
    for (int kk = 0; kk < 256; kk += 32) {
      int k8 = kk + quad * 8;
      const unsigned short* ap = (k8 < 128) ? (a.x[0] + (size_t)arow * 128 + k8)
                                            : (a.x[2] + (size_t)arow * 128 + (k8 - 128));
      s8v av = *(const s8v*)ap;
#pragma unroll
      for (int nt = 0; nt < 8; nt++) {
        s8v bv = *(const s8v*)(Wp + (size_t)(nt * 16 + l16) * 256 + k8);
        acc[nt] = __builtin_amdgcn_mfma_f32_16x16x32_bf16(av, bv, acc[nt], 0, 0, 0);
      }
    }
  }
  float* outp = a.out[o];
#pragma unroll
  for (int nt = 0; nt < 8; nt++) {
    int col = nt * 16 + l16;
    float bvv = loadf(a.b[o], col, wf32);
#pragma unroll
    for (int r = 0; r < 4; r++) {
      int row = m0 + quad * 4 + r;
      if (row < NN) {
        float v = acc[nt][r] + bvv;
        if (o == 7) v = fmaxf(v, 0.f);
        outp[(size_t)row * 128 + col] = v;
      }
    }
  }
}

// ---------------- sv kernel: Vj GEMM, 16x64 per wave -> sv[e] ----------------
// Block = 4 waves, 32 edges. Wave pair p=w>>1 shares 16 rows; hf=w&1 takes
// 64 cols. 4-acc tile -> 16 AGPR -> ~64 total regs -> ~8 waves/SIMD.
__global__ __launch_bounds__(256) void sv_kernel(
    const unsigned short* __restrict__ sh, const int* __restrict__ src,
    const int* __restrict__ dst, const unsigned short* __restrict__ WV,
    const void* __restrict__ bV, float* __restrict__ svout,
    const int* __restrict__ flags) {
  __shared__ float part[2][2][16];
  const int wave = threadIdx.x >> 6, lane = threadIdx.x & 63;
  const int l16 = lane & 15, quad = lane >> 4;
  const int p = wave >> 1, hf = wave & 1;
  const int m0 = blockIdx.x * 32 + p * 16;  // NE % 32 == 0
  const bool wf32 = flags[5] != 0;
  const int arow = m0 + l16;
  const int asrc = src[arow], adst = dst[arow];
  const unsigned short* hs_row = sh + (size_t)asrc * 128;
  const unsigned short* hd_row = sh + (size_t)adst * 128;
  f4v acc[4] = {};
#pragma unroll
  for (int kk = 0; kk < 128; kk += 32) {
    int k8 = kk + quad * 8;
    s8v hs = *(const s8v*)(hs_row + k8);
    s8v hd = *(const s8v*)(hd_row + k8);
    s8v ap;
#pragma unroll
    for (int j = 0; j < 8; j++)
      ap[j] = f2b(b2f((unsigned short)hs[j]) * b2f((unsigned short)hd[j]));
#pragma unroll
    for (int nt = 0; nt < 4; nt++) {
      int col = hf * 64 + nt * 16 + l16;
      s8v bv = *(const s8v*)(WV + (size_t)col * 128 + k8);
      acc[nt] = __builtin_amdgcn_mfma_f32_16x16x32_bf16(ap, bv, acc[nt], 0, 0, 0);
    }
  }
  float sv[4] = {0.f, 0.f, 0.f, 0.f};
#pragma unroll
  for (int nt = 0; nt < 4; nt++) {
    int col = hf * 64 + nt * 16 + l16;
    float bvv = loadf(bV, col, wf32);
#pragma unroll
    for (int r = 0; r < 4; r++) sv[r] += fmaxf(acc[nt][r] + bvv, 0.f);
  }
#pragma unroll
  for (int m = 1; m < 16; m <<= 1) {
#pragma unroll
    for (int r = 0; r < 4; r++) sv[r] += __shfl_xor(sv[r], m, 64);
  }
  if (l16 == 0) {
#pragma unroll
    for (int r = 0; r < 4; r++) part[p][hf][quad * 4 + r] = sv[r];
  }
  __syncthreads();
  if (hf == 0 && lane < 16)
    svout[m0 + lane] = part[p][0][lane] + part[p][1][lane];
}

// ---------------- fused edge kernel: E1 GEMM (16x64/wave) + epilogue ----------------
// Block = 4 waves, 32 edges. GEMM parks E1 (bf16) in block LDS; barrier;
// epilogue: each wave finalizes 8 rows x 128 cols with coalesced float2
// gathers, indices prefetched before the GEMM.
#define LSTR 136  // ushorts; 272B rows
__global__ __launch_bounds__(256) void edge_kernel(
    const void* __restrict__ e, const int* __restrict__ spatial,
    const int* __restrict__ src, const int* __restrict__ dst,
    const unsigned short* __restrict__ WE1, const void* __restrict__ bE1,
    const float* __restrict__ P1h, const float* __restrict__ P2h,
    const float* __restrict__ sv, float* __restrict__ fab,
    void* __restrict__ out, const int* __restrict__ flags) {
  __shared__ __align__(16) unsigned short lds_E1[32 * LSTR];
  const int wave = threadIdx.x >> 6, lane = threadIdx.x & 63;
  const int l16 = lane & 15, quad = lane >> 4;
  const int p = wave >> 1, hf = wave & 1;
  const int m0 = blockIdx.x * 32 + p * 16;  // NE % 32 == 0
  const bool ef32 = flags[1] != 0;
  const bool wf32 = flags[5] != 0;
  const bool of32 = (flags[0] | flags[1] | flags[2] | flags[3] | flags[4] | flags[5]) != 0;

  // prefetch this wave's epilogue indices (lane&7 -> row) before the GEMM
  const int myrow = blockIdx.x * 32 + wave * 8 + (lane & 7);
  const int pse = src[myrow], pde = dst[myrow], psp = spatial[myrow];

  // ---- E1 GEMM: rows m0..m0+15, cols hf*64..hf*64+63 ----
  const int arow = m0 + l16;
  const size_t ro = (size_t)arow * 128;
  f4v acc[4] = {};
#pragma unroll
  for (int kk = 0; kk < 128; kk += 32) {
    int k8 = kk + quad * 8;
    s8v av;
    if (ef32) av = cvt8((const float*)e + ro + k8);
    else av = *(const s8v*)((const unsigned short*)e + ro + k8);
#pragma unroll
    for (int nt = 0; nt < 4; nt++) {
      int col = hf * 64 + nt * 16 + l16;
      s8v bv = *(const s8v*)(WE1 + (size_t)col * 128 + k8);
      acc[nt] = __builtin_amdgcn_mfma_f32_16x16x32_bf16(av, bv, acc[nt], 0, 0, 0);
    }
  }
#pragma unroll
  for (int nt = 0; nt < 4; nt++) {
    int col = hf * 64 + nt * 16 + l16;
    float bvv = loadf(bE1, col, wf32);
#pragma unroll
    for (int r = 0; r < 4; r++) {
      int lrow = p * 16 + quad * 4 + r;  // block-local row 0..31
      lds_E1[lrow * LSTR + col] = (unsigned short)f2b(acc[nt][r] + bvv);
    }
  }
  __syncthreads();

  // ---- Epilogue: 8 rows per wave, 2 cols per lane ----
  const int c0 = lane * 2;
#pragma unroll 4
  for (int r = 0; r < 8; r++) {
    const int er = blockIdx.x * 32 + wave * 8 + r;
    const int sr_ = __shfl(pse, r, 64);
    const int dr_ = __shfl(pde, r, 64);
    const int sp_ = __shfl(psp, r, 64);
    float2 p1 = *(const float2*)(P1h + (size_t)dr_ * 128 + c0);
    float2 p2 = *(const float2*)(P2h + (size_t)sr_ * 128 + c0);
    unsigned int e1w = *(const unsigned int*)&lds_E1[(wave * 8 + r) * LSTR + c0];
    float e1x = b2f((unsigned short)(e1w & 0xFFFF));
    float e1y = b2f((unsigned short)(e1w >> 16));
    float2 ee = loadf2(e, (size_t)er * 128 + c0, ef32);
    float vx = 0.5f * (p1.x - p2.x + e1x);
    float vy = 0.5f * (p1.y - p2.y + e1y);
    storef2(out, OUT_E + (size_t)er * 128 + c0, ee.x + lrelu(vx), ee.y + lrelu(vy), of32);
    float n2 = vx * vx + vy * vy;
#pragma unroll
    for (int m = 1; m < 64; m <<= 1) n2 += __shfl_xor(n2, m, 64);
    if (sp_ == 1) {
      float n = sqrtf(n2);
      if (n >= 1e-9f) {
        float svr = sv[er];
        float rr = 0.5f * sqrtf(n);
        float s = expf(-rr / SIG);
        float c = -svr * s * 0.25f / (SIG * n * sqrtf(n));
        atomicAdd(&fab[(size_t)dr_ * 128 + c0], c * vx);
        atomicAdd(&fab[(size_t)dr_ * 128 + c0 + 1], c * vy);
      }
    }
  }
}

// ---------------- node finalize ----------------
__global__ __launch_bounds__(256) void node_out_kernel(
    const unsigned short* __restrict__ sh, const unsigned short* __restrict__ sp,
    const unsigned short* __restrict__ sd, const void* __restrict__ dt,
    const float* __restrict__ V1h, const float* __restrict__ V2h, const float* __restrict__ P3h,
    const float* __restrict__ D1h, const float* __restrict__ D2h, const float* __restrict__ g,
    const float* __restrict__ fab, const float* __restrict__ cnt,
    void* __restrict__ out, const int* __restrict__ flags) {
  const int wave = threadIdx.x >> 6, lane = threadIdx.x & 63;
  const int node = blockIdx.x * 4 + wave;  // NN % 4 == 0
  const bool dtf32 = flags[4] != 0;
  const bool of32 = (flags[0] | flags[1] | flags[2] | flags[3] | flags[4] | flags[5]) != 0;
  const size_t i = (size_t)node * 128 + lane * 2;
  float cn = cnt[node];
  float2 v1 = *(const float2*)(V1h + i);
  float2 d1 = *(const float2*)(D1h + i);
  float2 gg = *(const float2*)(g + i);
  float2 fb = *(const float2*)(fab + i);
  float fx = (d1.x - v1.x) * (cn * gg.x) - fb.x;
  float fy = (d1.y - v1.y) * (cn * gg.y) - fb.y;
  float n2 = fx * fx + fy * fy;
#pragma unroll
  for (int m = 1; m < 64; m <<= 1) n2 += __shfl_xor(n2, m, 64);
  float nf = sqrtf(n2);
  float dtv = loadf(dt, node, dtf32);
  float2 v2 = *(const float2*)(V2h + i);
  float2 p3 = *(const float2*)(P3h + i);
  float2 d2 = *(const float2*)(D2h + i);
  float hx = v2.x + fx * dtv, hy = v2.y + fy * dtv;
  float px = p3.x + fx * dtv + 0.5f * fx * dtv * dtv;
  float py = p3.y + fy * dtv + 0.5f * fy * dtv * dtv;
  float invn = 1.f / (nf + 1e-9f);
  float dx = d2.x + fx * invn, dy = d2.y + fy * invn;
  storef2(out, OUT_H + i, b2f(sh[i]) + lrelu(hx), b2f(sh[i + 1]) + lrelu(hy), of32);
  storef2(out, OUT_P + i, b2f(sp[i]) + lrelu(px), b2f(sp[i + 1]) + lrelu(py), of32);
  storef2(out, OUT_D + i, b2f(sd[i]) + lrelu(dx), b2f(sd[i + 1]) + lrelu(dy), of32);
}

extern "C" void kernel_launch(void* const* d_in, const int* in_sizes, int n_in,
                              void* d_out, int out_size, void* d_ws, size_t ws_size,
                              hipStream_t stream) {
  const int* spatial = (const int*)d_in[5];
  const int* src = (const int*)d_in[6];
  const int* dst = (const int*)d_in[7];

  float* ws = (float*)d_ws;
  int* flags = (int*)(ws + F_FLAGS);
  unsigned short* stg = (unsigned short*)(ws + F_STAGED);

  zero_kernel<<<(int)(NDp / 256), 256, 0, stream>>>(ws);

  DetArgs da;
  da.t[0] = { (const unsigned short*)d_in[0], 1280000, 0 };
  da.t[1] = { (const unsigned short*)d_in[1], 40960000, 1 };
  da.t[2] = { (const unsigned short*)d_in[2], 1280000, 2 };
  da.t[3] = { (const unsigned short*)d_in[3], 1280000, 3 };
  da.t[4] = { (const unsigned short*)d_in[4], 10000, 4 };
  da.t[5] = { (const unsigned short*)d_in[8], 16384, 5 };
  da.flags = flags;
  detect_kernel<<<dim3(1024, 6), 256, 0, stream>>>(da);

  ConvArgs ca;
  ca.t[0] = { d_in[0], stg + S_H, 1280000, 0 };
  ca.t[1] = { d_in[2], stg + S_P, 1280000, 2 };
  ca.t[2] = { d_in[3], stg + S_D, 1280000, 3 };
  for (int i = 0; i < 9; i++)
    ca.t[3 + i] = { d_in[8 + 2 * i], stg + S_W + (size_t)i * 16384, 16384, 5 };
  ca.t[12] = { d_in[26], stg + S_WT, 32768, 5 };
  ca.flags = flags;
  convert_kernel<<<dim3(640, 13), 256, 0, stream>>>(ca);

  cnt_kernel<<<NE / 256, 256, 0, stream>>>(spatial, dst, ws + F_CNT);

  sv_kernel<<<NE / 32, 256, 0, stream>>>(
      stg + S_H, src, dst, stg + S_W + 8 * 16384, d_in[25], ws + F_SV, flags);

  NodeArgs na;
  na.x[0] = stg + S_H; na.x[1] = stg + S_P; na.x[2] = stg + S_D;
  na.W[0] = stg + S_W + 0 * 16384;  na.b[0] = d_in[9];   // V1
  na.W[1] = stg + S_W + 1 * 16384;  na.b[1] = d_in[11];  // V2
  na.W[2] = stg + S_W + 3 * 16384;  na.b[2] = d_in[15];  // P1
  na.W[3] = stg + S_W + 4 * 16384;  na.b[3] = d_in[17];  // P2
  na.W[4] = stg + S_W + 5 * 16384;  na.b[4] = d_in[19];  // P3
  na.W[5] = stg + S_W + 6 * 16384;  na.b[5] = d_in[21];  // D1
  na.W[6] = stg + S_W + 7 * 16384;  na.b[6] = d_in[23];  // D2
  na.W[7] = stg + S_WT;             na.b[7] = d_in[27];  // T
  na.out[0] = ws + F_V1H; na.out[1] = ws + F_V2H; na.out[2] = ws + F_P1H;
  na.out[3] = ws + F_P2H; na.out[4] = ws + F_P3H; na.out[5] = ws + F_D1H;
  na.out[6] = ws + F_D2H; na.out[7] = ws + F_G;
  na.flags = flags;
  node_gemm_kernel<<<dim3((NN + 63) / 64, 8), 256, 0, stream>>>(na);

  edge_kernel<<<NE / 32, 256, 0, stream>>>(
      d_in[1], spatial, src, dst,
      stg + S_W + 2 * 16384, d_in[13],
      ws + F_P1H, ws + F_P2H, ws + F_SV, ws + F_FAB, d_out, flags);

  node_out_kernel<<<NN / 4, 256, 0, stream>>>(
      stg + S_H, stg + S_P, stg + S_D, d_in[4],
      ws + F_V1H, ws + F_V2H, ws + F_P3H, ws + F_D1H, ws + F_D2H, ws + F_G,
      ws + F_FAB, ws + F_CNT, d_out, flags);
}